// Round 1
// baseline (300.454 us; speedup 1.0000x reference)
//
#include <hip/hip_runtime.h>
#include <hip/hip_bf16.h>
#include <math.h>

typedef __bf16 bf16_t;
typedef __bf16 bf16x8 __attribute__((ext_vector_type(8)));
typedef float f32x4 __attribute__((ext_vector_type(4)));

#define QEPS 1e-5

__device__ __forceinline__ void gload_lds16(const void* g, void* l) {
  __builtin_amdgcn_global_load_lds((const __attribute__((address_space(1))) void*)g,
                                   (__attribute__((address_space(3))) void*)l, 16, 0, 0);
}

// exact GELU via A&S 7.1.26 erf (|err| <= 1.5e-7), branchless
__device__ __forceinline__ float gelu_exact(float x) {
  float a = x * 0.7071067811865476f;
  float s = fabsf(a);
  float t = __builtin_amdgcn_rcpf(__builtin_fmaf(0.3275911f, s, 1.0f));
  float p = __builtin_fmaf(1.061405429f, t, -1.453152027f);
  p = __builtin_fmaf(p, t, 1.421413741f);
  p = __builtin_fmaf(p, t, -0.284496736f);
  p = __builtin_fmaf(p, t, 0.254829592f);
  p = p * t;
  float e = __expf(-s * s);
  float er = copysignf(__builtin_fmaf(-p, e, 1.0f), a);
  return 0.5f * x * (1.0f + er);
}

// ---- P1: per-block fp64 partial sums of |w| ----
__global__ void reduce_part_kernel(const float* __restrict__ w1, const float* __restrict__ w2,
                                   int n, double* __restrict__ part) {
  const bool second = blockIdx.x >= 256;
  const float* __restrict__ w = second ? w2 : w1;
  const int b = second ? blockIdx.x - 256 : blockIdx.x;
  double s = 0.0;
  const int stride = 256 * 256 * 4;
  for (int i = (b * 256 + threadIdx.x) * 4; i < n; i += stride) {
    float4 v = *(const float4*)(w + i);
    s += (double)fabsf(v.x) + (double)fabsf(v.y) + (double)fabsf(v.z) + (double)fabsf(v.w);
  }
  for (int off = 32; off > 0; off >>= 1)
    s += __shfl_down(s, off, 64);
  __shared__ double ls[4];
  int lane = threadIdx.x & 63, wv = threadIdx.x >> 6;
  if (lane == 0) ls[wv] = s;
  __syncthreads();
  if (threadIdx.x == 0) part[blockIdx.x] = ls[0] + ls[1] + ls[2] + ls[3];
}

// ---- P2: quantize w1,w2 + cast/pad x into BLOCKED+SWIZZLED 128x64 tiles ----
// Tile = 128 rows x 64 k-cols bf16 (8192 elems, 16 KB). 16-B chunk index
// (r*8 + slot) holds row r, k-chunk (slot ^ (r&7)) -- the exact image
// global_load_lds linear staging produces, so GEMM frag reads at
// chunk = (ksub*4+quad) ^ (row16&7) are fully bank-conflict-free
// (each consecutive 8-lane group covers all 8 bank-quads).
__global__ void prep_kernel(const float* __restrict__ w1, const float* __restrict__ w2,
                            const float* __restrict__ x, const double* __restrict__ part,
                            double* __restrict__ gammas, bf16_t* __restrict__ q1,
                            bf16_t* __restrict__ q2, bf16_t* __restrict__ xb) {
  const int tid = threadIdx.x;
  const int b = blockIdx.x;
  if (b < 2304) {                      // weight quantize: 1152 blocks each
    const bool second = b >= 1152;
    double p = part[(second ? 256 : 0) + tid];
    for (int off = 32; off > 0; off >>= 1)
      p += __shfl_down(p, off, 64);
    __shared__ double red[4];
    if ((tid & 63) == 0) red[tid >> 6] = p;
    __syncthreads();
    const double g = (red[0] + red[1] + red[2] + red[3]) / 2359296.0 + QEPS;
    if (tid == 0 && (b == 0 || b == 1152)) gammas[second ? 1 : 0] = g;
    const double rg = 1.0 / g;
    const int gchunk = (second ? b - 1152 : b) * 256 + tid;   // < 294912
    const int tile = gchunk >> 10, cidx = gchunk & 1023;
    const int r = cidx >> 3, slot = cidx & 7, kc = slot ^ (r & 7);
    int row, col, C;
    const float* __restrict__ W;
    if (second) { C = 3072; W = w2; row = (tile / 48) * 128 + r; col = (tile % 48) * 64 + kc * 8; }
    else        { C = 768;  W = w1; row = (tile / 12) * 128 + r; col = (tile % 12) * 64 + kc * 8; }
    const float4 v0 = *(const float4*)(W + (size_t)row * C + col);
    const float4 v1 = *(const float4*)(W + (size_t)row * C + col + 4);
    bf16x8 o;
    o[0] = (bf16_t)(float)fmin(1.0, fmax(-1.0, rint((double)v0.x * rg)));
    o[1] = (bf16_t)(float)fmin(1.0, fmax(-1.0, rint((double)v0.y * rg)));
    o[2] = (bf16_t)(float)fmin(1.0, fmax(-1.0, rint((double)v0.z * rg)));
    o[3] = (bf16_t)(float)fmin(1.0, fmax(-1.0, rint((double)v0.w * rg)));
    o[4] = (bf16_t)(float)fmin(1.0, fmax(-1.0, rint((double)v1.x * rg)));
    o[5] = (bf16_t)(float)fmin(1.0, fmax(-1.0, rint((double)v1.y * rg)));
    o[6] = (bf16_t)(float)fmin(1.0, fmax(-1.0, rint((double)v1.z * rg)));
    o[7] = (bf16_t)(float)fmin(1.0, fmax(-1.0, rint((double)v1.w * rg)));
    *(bf16x8*)((second ? q2 : q1) + (size_t)gchunk * 8) = o;
  } else {                             // x cast/pad: 4800 blocks (12800 rows)
    const int gchunk = (b - 2304) * 256 + tid;                // < 1228800
    const int tile = gchunk >> 10, cidx = gchunk & 1023;
    const int r = cidx >> 3, slot = cidx & 7, kc = slot ^ (r & 7);
    const int row = (tile / 12) * 128 + r;
    const int col = (tile % 12) * 64 + kc * 8;
    bf16x8 o;
    if (row < 12608) {
      const float4 v0 = *(const float4*)(x + (size_t)row * 768 + col);
      const float4 v1 = *(const float4*)(x + (size_t)row * 768 + col + 4);
      o[0] = (bf16_t)v0.x; o[1] = (bf16_t)v0.y; o[2] = (bf16_t)v0.z; o[3] = (bf16_t)v0.w;
      o[4] = (bf16_t)v1.x; o[5] = (bf16_t)v1.y; o[6] = (bf16_t)v1.z; o[7] = (bf16_t)v1.w;
    } else {
      o = bf16x8{};
    }
    *(bf16x8*)(xb + (size_t)gchunk * 8) = o;
  }
}

// ---- GEMM: 256x256 block, BK=64, 512 threads (8 waves), 8-phase-style
// schedule: 4 phases per K-tile (one C-quadrant each), one half-tile
// (128r x 64k, 2 x global_load_lds) staged per phase, counted vmcnt(4)
// once per K-tile (never 0 in steady state). LDS = 8 x 16KB slots (128KB,
// dynamic). Stage ledger (group T = K-tile T, buf = T&1):
//   g1 Q(0,0): read A0,B0  | stage B1(T+1) -> slot[buf^1]  (B1(T-1) last read g2(T-1))
//   g2 Q(0,1): read B1     | stage A1(T+1) -> slot[buf^1]  (A1(T-1) last read g3(T-1))
//   g3 Q(1,0): read A1     | stage A0(T+2) -> slot[buf]    (A0(T)   last read g1(T))
//   g4 Q(1,1): (regs only) | stage B0(T+2) -> slot[buf]    (B0(T)   last read g1(T))
//              vmcnt(4) -> everything except {A0(T+2),B0(T+2)} complete
// EPI==0: hb tiles (blocked+swizzled bf16) = gelu(gamma*acc + bias), via LDS
// EPI==1: fp32 row-major out (stride aux), rows < Mvalid
template <int EPI>
__global__ __launch_bounds__(512, 2)
void gemm8(const bf16_t* __restrict__ A, const bf16_t* __restrict__ B,
           const float* __restrict__ bias, const double* __restrict__ gptr,
           void* __restrict__ Cout, int nkt, int gx, int Mvalid, int aux) {
  extern __shared__ bf16_t smem[];     // 65536 elems = 128 KB

  // bijective XCD-chunked tile id
  const int G = gridDim.x;
  const int f = blockIdx.x;
  const int xcd = f & 7;
  const int idx = f >> 3;
  const int q8 = G >> 3, r8 = G & 7;
  const int t = xcd * q8 + (xcd < r8 ? xcd : r8) + idx;
  const int bx = t % gx;
  const int by = t / gx;

  const int tid = threadIdx.x;
  const int lane = tid & 63;
  const int wave = tid >> 6;
  const int row16 = lane & 15;
  const int quad = lane >> 4;
  const int ww = wave >> 2;            // 0..1 : 64-row group within quadrant
  const int wcol = wave & 3;           // 0..3 : 32-col group within quadrant

  const int sw0 = (quad ^ (row16 & 7)) * 8;
  const int aoff0 = row16 * 64 + sw0;          // ksub 0 lane offset
  const int aoff1 = row16 * 64 + (sw0 ^ 32);   // ksub 1 lane offset
  const int wwoff = ww * 4096;
  const int bcoff = wcol * 2048;

  const bf16_t* const Ab = A + (size_t)(by * 2) * nkt * 8192;
  const bf16_t* const Bb = B + (size_t)(bx * 2) * nkt * 8192;

  f32x4 acc[8][4] = {};
  bf16x8 aw[8], bw0[4], bw1[4];

#define SA_(bufv, h) (smem + (((bufv) * 2 + (h)) * 8192))
#define SB_(bufv, h) (smem + 32768 + (((bufv) * 2 + (h)) * 8192))
#define SRCA_(T, h) (Ab + ((size_t)(h) * nkt + (T)) * 8192)
#define SRCB_(T, h) (Bb + ((size_t)(h) * nkt + (T)) * 8192)
#define STAGE_(src, dst) do { \
    gload_lds16((src) + tid * 8, (dst) + wave * 512); \
    gload_lds16((src) + 4096 + tid * 8, (dst) + 4096 + wave * 512); } while (0)
#define LDA_(bufv, h) do { \
    const bf16_t* p0_ = SA_(bufv, h) + wwoff + aoff0; \
    const bf16_t* p1_ = SA_(bufv, h) + wwoff + aoff1; \
    aw[0] = *(const bf16x8*)(p0_);        aw[1] = *(const bf16x8*)(p1_); \
    aw[2] = *(const bf16x8*)(p0_ + 1024); aw[3] = *(const bf16x8*)(p1_ + 1024); \
    aw[4] = *(const bf16x8*)(p0_ + 2048); aw[5] = *(const bf16x8*)(p1_ + 2048); \
    aw[6] = *(const bf16x8*)(p0_ + 3072); aw[7] = *(const bf16x8*)(p1_ + 3072); } while (0)
#define LDB_(arr, bufv, h) do { \
    const bf16_t* p0_ = SB_(bufv, h) + bcoff + aoff0; \
    const bf16_t* p1_ = SB_(bufv, h) + bcoff + aoff1; \
    arr[0] = *(const bf16x8*)(p0_);        arr[1] = *(const bf16x8*)(p1_); \
    arr[2] = *(const bf16x8*)(p0_ + 1024); arr[3] = *(const bf16x8*)(p1_ + 1024); } while (0)
#define MMQ_(BW, AM0, AN0) do { \
    __builtin_amdgcn_s_setprio(1); \
    _Pragma("unroll") for (int m_ = 0; m_ < 4; m_++) \
    _Pragma("unroll") for (int n_ = 0; n_ < 2; n_++) \
    _Pragma("unroll") for (int k_ = 0; k_ < 2; k_++) \
      acc[(AM0) + m_][(AN0) + n_] = __builtin_amdgcn_mfma_f32_16x16x32_bf16( \
          aw[2 * m_ + k_], BW[2 * n_ + k_], acc[(AM0) + m_][(AN0) + n_], 0, 0, 0); \
    __builtin_amdgcn_s_setprio(0); } while (0)

  // prologue: tile0 (A0,B0,B1,A1) + tile1 (A0,B0); allow last 2 halves in flight
  STAGE_(SRCA_(0, 0), SA_(0, 0));
  STAGE_(SRCB_(0, 0), SB_(0, 0));
  STAGE_(SRCB_(0, 1), SB_(0, 1));
  STAGE_(SRCA_(0, 1), SA_(0, 1));
  STAGE_(SRCA_(1, 0), SA_(1, 0));
  STAGE_(SRCB_(1, 0), SB_(1, 0));
  asm volatile("s_waitcnt vmcnt(4)" ::: "memory");
  __builtin_amdgcn_s_barrier();

  for (int T = 0; T < nkt; T++) {
    const int buf = T & 1;
    // ---- g1: Q(0,0) ----
    LDA_(buf, 0);
    LDB_(bw0, buf, 0);
    if (T + 1 < nkt) STAGE_(SRCB_(T + 1, 1), SB_(buf ^ 1, 1));
    __builtin_amdgcn_s_barrier();
    MMQ_(bw0, 0, 0);
    __builtin_amdgcn_s_barrier();
    // ---- g2: Q(0,1) ----
    LDB_(bw1, buf, 1);
    if (T + 1 < nkt) STAGE_(SRCA_(T + 1, 1), SA_(buf ^ 1, 1));
    __builtin_amdgcn_s_barrier();
    MMQ_(bw1, 0, 2);
    __builtin_amdgcn_s_barrier();
    // ---- g3: Q(1,0) ----
    LDA_(buf, 1);
    if (T + 2 < nkt) STAGE_(SRCA_(T + 2, 0), SA_(buf, 0));
    __builtin_amdgcn_s_barrier();
    MMQ_(bw0, 4, 0);
    __builtin_amdgcn_s_barrier();
    // ---- g4: Q(1,1) ----
    if (T + 2 < nkt) STAGE_(SRCB_(T + 2, 0), SB_(buf, 0));
    __builtin_amdgcn_s_barrier();
    MMQ_(bw1, 4, 2);
    if (T + 2 < nkt) asm volatile("s_waitcnt vmcnt(4)" ::: "memory");
    else             asm volatile("s_waitcnt vmcnt(0)" ::: "memory");
    __builtin_amdgcn_s_barrier();
  }

  const float gamma = (float)gptr[0];

  float bv[4];
  int cbv[4];
#pragma unroll
  for (int an = 0; an < 4; an++) {
    cbv[an] = (an >> 1) * 128 + wcol * 32 + (an & 1) * 16 + row16;
    bv[an] = bias[bx * 256 + cbv[an]];
  }

  if constexpr (EPI == 0) {
    // h = gelu(gamma*acc + bias), written in blocked+swizzled 128x64-tile
    // layout via full-LDS staging (8 local tiles = 128KB = this block's C).
    bf16_t* sE = smem;
#pragma unroll
    for (int am = 0; am < 8; am++) {
      const int rtile = am >> 2;
      const int rbase = ww * 64 + (am & 3) * 16 + quad * 4;   // within 128
#pragma unroll
      for (int an = 0; an < 4; an++) {
        const int cb = cbv[an];
        const int ltile = rtile * 4 + (cb >> 6);
        const int kc = (cb >> 3) & 7, e = cb & 7;
#pragma unroll
        for (int r = 0; r < 4; r++) {
          const int rin = rbase + r;
          sE[ltile * 8192 + (rin * 8 + (kc ^ (rin & 7))) * 8 + e] =
              (bf16_t)gelu_exact(__builtin_fmaf(gamma, acc[am][an][r], bv[an]));
        }
      }
    }
    __syncthreads();
    bf16_t* hb = (bf16_t*)Cout;                 // aux = nkt of h (H/64)
#pragma unroll
    for (int i = 0; i < 16; i++) {
      const int gc = i * 512 + tid;
      const int lt = gc >> 10, ci = gc & 1023;
      const int rg = by * 2 + (lt >> 2), kg = bx * 4 + (lt & 3);
      *(bf16x8*)(hb + ((size_t)rg * aux + kg) * 8192 + ci * 8) = *(const bf16x8*)(sE + gc * 8);
    }
  } else {
    float* outp = (float*)Cout;                 // aux = row stride (=768)
#pragma unroll
    for (int am = 0; am < 8; am++) {
      const int rbase = by * 256 + (am >> 2) * 128 + ww * 64 + (am & 3) * 16 + quad * 4;
#pragma unroll
      for (int an = 0; an < 4; an++) {
        const int col = bx * 256 + cbv[an];
#pragma unroll
        for (int r = 0; r < 4; r++) {
          const int row = rbase + r;
          if (row < Mvalid)
            outp[(size_t)row * aux + col] = __builtin_fmaf(gamma, acc[am][an][r], bv[an]);
        }
      }
    }
  }
#undef SA_
#undef SB_
#undef SRCA_
#undef SRCB_
#undef STAGE_
#undef LDA_
#undef LDB_
#undef MMQ_
}

extern "C" void kernel_launch(void* const* d_in, const int* in_sizes, int n_in,
                              void* d_out, int out_size, void* d_ws, size_t ws_size,
                              hipStream_t stream) {
  const float* x  = (const float*)d_in[0];
  const float* w1 = (const float*)d_in[1];
  const float* b1 = (const float*)d_in[2];
  const float* w2 = (const float*)d_in[3];
  const float* b2 = (const float*)d_in[4];
  float* out = (float*)d_out;

  const int M = 64 * 197;      // 12608
  const int Mpad = 12800;      // 50 * 256
  const int D = 768, H = 3072;
  const int nW = H * D;        // 2359296

  char* ws = (char*)d_ws;
  double* part = (double*)ws;                      // [512] @ ws[0,4096)
  double* gammas = (double*)(ws + 4096);           // [2] own cacheline
  bf16_t* xb  = (bf16_t*)(ws + 4096 + 256);        // 100x12 tiles of 128x64
  bf16_t* w1q = xb + (size_t)Mpad * D;             // 24x12 tiles
  bf16_t* w2q = w1q + (size_t)H * D;               // 6x48 tiles
  bf16_t* hb  = w2q + (size_t)D * H;               // 100x48 tiles

  static bool attr_done = false;
  if (!attr_done) {
    (void)hipFuncSetAttribute(reinterpret_cast<const void*>(&gemm8<0>),
                              hipFuncAttributeMaxDynamicSharedMemorySize, 131072);
    (void)hipFuncSetAttribute(reinterpret_cast<const void*>(&gemm8<1>),
                              hipFuncAttributeMaxDynamicSharedMemorySize, 131072);
    attr_done = true;
  }

  reduce_part_kernel<<<512, 256, 0, stream>>>(w1, w2, nW, part);
  prep_kernel<<<2304 + 4800, 256, 0, stream>>>(w1, w2, x, part, gammas, w1q, w2q, xb);

  // GEMM1: 256x256 blocks, grid 50*12; A=xb(nkt=12), B=w1q -> hb blocked
  gemm8<0><<<50 * 12, 512, 131072, stream>>>(xb, w1q, b1, gammas + 0, hb, 12, 12, M, H / 64);
  // GEMM2: 256x256 blocks, grid 50*3; A=hb(nkt=48), B=w2q -> fp32 out
  gemm8<1><<<50 * 3, 512, 131072, stream>>>(hb, w2q, b2, gammas + 1, out, 48, 3, M, D);
}

// Round 2
// 275.025 us; speedup vs baseline: 1.0925x; 1.0925x over previous
//
#include <hip/hip_runtime.h>
#include <hip/hip_bf16.h>
#include <math.h>

typedef __bf16 bf16_t;
typedef __bf16 bf16x8 __attribute__((ext_vector_type(8)));
typedef float f32x4 __attribute__((ext_vector_type(4)));

#define QEPS 1e-5

__device__ __forceinline__ void gload_lds16(const void* g, void* l) {
  __builtin_amdgcn_global_load_lds((const __attribute__((address_space(1))) void*)g,
                                   (__attribute__((address_space(3))) void*)l, 16, 0, 0);
}

// exact GELU via A&S 7.1.26 erf (|err| <= 1.5e-7), branchless
__device__ __forceinline__ float gelu_exact(float x) {
  float a = x * 0.7071067811865476f;
  float s = fabsf(a);
  float t = __builtin_amdgcn_rcpf(__builtin_fmaf(0.3275911f, s, 1.0f));
  float p = __builtin_fmaf(1.061405429f, t, -1.453152027f);
  p = __builtin_fmaf(p, t, 1.421413741f);
  p = __builtin_fmaf(p, t, -0.284496736f);
  p = __builtin_fmaf(p, t, 0.254829592f);
  p = p * t;
  float e = __expf(-s * s);
  float er = copysignf(__builtin_fmaf(-p, e, 1.0f), a);
  return 0.5f * x * (1.0f + er);
}

// ---- P1: per-block fp64 partial sums of |w| ----
__global__ void reduce_part_kernel(const float* __restrict__ w1, const float* __restrict__ w2,
                                   int n, double* __restrict__ part) {
  const bool second = blockIdx.x >= 256;
  const float* __restrict__ w = second ? w2 : w1;
  const int b = second ? blockIdx.x - 256 : blockIdx.x;
  double s = 0.0;
  const int stride = 256 * 256 * 4;
  for (int i = (b * 256 + threadIdx.x) * 4; i < n; i += stride) {
    float4 v = *(const float4*)(w + i);
    s += (double)fabsf(v.x) + (double)fabsf(v.y) + (double)fabsf(v.z) + (double)fabsf(v.w);
  }
  for (int off = 32; off > 0; off >>= 1)
    s += __shfl_down(s, off, 64);
  __shared__ double ls[4];
  int lane = threadIdx.x & 63, wv = threadIdx.x >> 6;
  if (lane == 0) ls[wv] = s;
  __syncthreads();
  if (threadIdx.x == 0) part[blockIdx.x] = ls[0] + ls[1] + ls[2] + ls[3];
}

// ---- P2: quantize w1,w2 + cast/pad x into BLOCKED+SWIZZLED 128x64 tiles ----
// Tile = 128 rows x 64 k-cols bf16 (8192 elems, 16 KB). 16-B chunk index
// (r*8 + slot) holds row r, k-chunk (slot ^ (r&7)) -- the exact image
// global_load_lds linear staging produces, so GEMM frag reads at
// chunk = (ksub*4+quad) ^ (row16&7) are fully bank-conflict-free
// (PROVEN: round-1 measured SQ_LDS_BANK_CONFLICT == 0 with this layout).
__global__ void prep_kernel(const float* __restrict__ w1, const float* __restrict__ w2,
                            const float* __restrict__ x, const double* __restrict__ part,
                            double* __restrict__ gammas, bf16_t* __restrict__ q1,
                            bf16_t* __restrict__ q2, bf16_t* __restrict__ xb) {
  const int tid = threadIdx.x;
  const int b = blockIdx.x;
  if (b < 2304) {                      // weight quantize: 1152 blocks each
    const bool second = b >= 1152;
    double p = part[(second ? 256 : 0) + tid];
    for (int off = 32; off > 0; off >>= 1)
      p += __shfl_down(p, off, 64);
    __shared__ double red[4];
    if ((tid & 63) == 0) red[tid >> 6] = p;
    __syncthreads();
    const double g = (red[0] + red[1] + red[2] + red[3]) / 2359296.0 + QEPS;
    if (tid == 0 && (b == 0 || b == 1152)) gammas[second ? 1 : 0] = g;
    const double rg = 1.0 / g;
    const int gchunk = (second ? b - 1152 : b) * 256 + tid;   // < 294912
    const int tile = gchunk >> 10, cidx = gchunk & 1023;
    const int r = cidx >> 3, slot = cidx & 7, kc = slot ^ (r & 7);
    int row, col, C;
    const float* __restrict__ W;
    if (second) { C = 3072; W = w2; row = (tile / 48) * 128 + r; col = (tile % 48) * 64 + kc * 8; }
    else        { C = 768;  W = w1; row = (tile / 12) * 128 + r; col = (tile % 12) * 64 + kc * 8; }
    const float4 v0 = *(const float4*)(W + (size_t)row * C + col);
    const float4 v1 = *(const float4*)(W + (size_t)row * C + col + 4);
    bf16x8 o;
    o[0] = (bf16_t)(float)fmin(1.0, fmax(-1.0, rint((double)v0.x * rg)));
    o[1] = (bf16_t)(float)fmin(1.0, fmax(-1.0, rint((double)v0.y * rg)));
    o[2] = (bf16_t)(float)fmin(1.0, fmax(-1.0, rint((double)v0.z * rg)));
    o[3] = (bf16_t)(float)fmin(1.0, fmax(-1.0, rint((double)v0.w * rg)));
    o[4] = (bf16_t)(float)fmin(1.0, fmax(-1.0, rint((double)v1.x * rg)));
    o[5] = (bf16_t)(float)fmin(1.0, fmax(-1.0, rint((double)v1.y * rg)));
    o[6] = (bf16_t)(float)fmin(1.0, fmax(-1.0, rint((double)v1.z * rg)));
    o[7] = (bf16_t)(float)fmin(1.0, fmax(-1.0, rint((double)v1.w * rg)));
    *(bf16x8*)((second ? q2 : q1) + (size_t)gchunk * 8) = o;
  } else {                             // x cast/pad: 4800 blocks (12800 rows)
    const int gchunk = (b - 2304) * 256 + tid;                // < 1228800
    const int tile = gchunk >> 10, cidx = gchunk & 1023;
    const int r = cidx >> 3, slot = cidx & 7, kc = slot ^ (r & 7);
    const int row = (tile / 12) * 128 + r;
    const int col = (tile % 12) * 64 + kc * 8;
    bf16x8 o;
    if (row < 12608) {
      const float4 v0 = *(const float4*)(x + (size_t)row * 768 + col);
      const float4 v1 = *(const float4*)(x + (size_t)row * 768 + col + 4);
      o[0] = (bf16_t)v0.x; o[1] = (bf16_t)v0.y; o[2] = (bf16_t)v0.z; o[3] = (bf16_t)v0.w;
      o[4] = (bf16_t)v1.x; o[5] = (bf16_t)v1.y; o[6] = (bf16_t)v1.z; o[7] = (bf16_t)v1.w;
    } else {
      o = bf16x8{};
    }
    *(bf16x8*)(xb + (size_t)gchunk * 8) = o;
  }
}

// ---- GEMM: 128x128 block, BK=64, 256 threads (4 waves, 2x2 wave grid,
// 64x64 per wave). Round-0-proven 2-barrier dbuf loop: prefetch K-tile T+1
// into buf^1 BEFORE computing T; one __syncthreads per iter (its implicit
// vmcnt(0)+lgkmcnt(0) drain is the handoff). LDS = 64 KB -> 2 blocks/CU:
// inter-block TLP hides the barrier drain (the mechanism that made round-0
// fast and whose absence at 1 block/CU sank round-1). Frag reads use the
// conflict-free 8-chunk XOR layout (round-1: 0 conflicts).
// EPI==0: hb tiles (blocked+swizzled bf16) = gelu(gamma*acc + bias), via LDS
// EPI==1: fp32 row-major out (stride aux), rows < Mvalid
template <int EPI>
__global__ __launch_bounds__(256, 2)
void gemm_db(const bf16_t* __restrict__ A, const bf16_t* __restrict__ B,
             const float* __restrict__ bias, const double* __restrict__ gptr,
             void* __restrict__ Cout, int nkt, int gx, int Mvalid, int aux) {
  extern __shared__ bf16_t sm[];   // 32768 elems = 64 KB: A[2][8192] | B[2][8192]

  // bijective XCD-chunked tile id (grid % 8 == 0 for both launches)
  const int G = gridDim.x;
  const int f = blockIdx.x;
  const int xcd = f & 7;
  const int idx = f >> 3;
  const int q8 = G >> 3, r8 = G & 7;
  const int t = xcd * q8 + (xcd < r8 ? xcd : r8) + idx;
  const int bx = t % gx;
  const int by = t / gx;

  const int tid = threadIdx.x;
  const int lane = tid & 63;
  const int wave = tid >> 6;
  const int row16 = lane & 15;
  const int quad = lane >> 4;
  const int wr = (wave >> 1) * 64;
  const int wc = (wave & 1) * 64;
  const int sw0 = (quad ^ (row16 & 7)) * 8;   // ksub0 chunk slot
  const int sw1 = sw0 ^ 32;                   // ksub1: chunk ^ 4

  const bf16_t* const gA = A + (size_t)by * nkt * 8192;
  const bf16_t* const gB = B + (size_t)bx * nkt * 8192;

  f32x4 acc[4][4] = {};

  const int o8 = tid * 8;
  const int w512 = wave * 512;

  // stage K-tile 0 into buffer 0 (8 x global_load_lds width-16)
#pragma unroll
  for (int l = 0; l < 4; l++) {
    gload_lds16(gA + l * 2048 + o8, sm + l * 2048 + w512);
    gload_lds16(gB + l * 2048 + o8, sm + 16384 + l * 2048 + w512);
  }
  __syncthreads();

  int p = 0;
  for (int T = 0; T < nkt; T++) {
    if (T + 1 < nkt) {                 // prefetch next tile into buf p^1
      const bf16_t* sa = gA + (size_t)(T + 1) * 8192;
      const bf16_t* sb = gB + (size_t)(T + 1) * 8192;
      bf16_t* dA = sm + (p ^ 1) * 8192;
      bf16_t* dB = sm + 16384 + (p ^ 1) * 8192;
#pragma unroll
      for (int l = 0; l < 4; l++) {
        gload_lds16(sa + l * 2048 + o8, dA + l * 2048 + w512);
        gload_lds16(sb + l * 2048 + o8, dB + l * 2048 + w512);
      }
    }
    const bf16_t* sA = sm + p * 8192;
    const bf16_t* sB = sm + 16384 + p * 8192;
    bf16x8 aw[4][2], bw[4][2];
#pragma unroll
    for (int i = 0; i < 4; i++) {
      const bf16_t* pr = sA + (wr + i * 16 + row16) * 64;
      aw[i][0] = *(const bf16x8*)(pr + sw0);
      aw[i][1] = *(const bf16x8*)(pr + sw1);
    }
#pragma unroll
    for (int j = 0; j < 4; j++) {
      const bf16_t* pr = sB + (wc + j * 16 + row16) * 64;
      bw[j][0] = *(const bf16x8*)(pr + sw0);
      bw[j][1] = *(const bf16x8*)(pr + sw1);
    }
#pragma unroll
    for (int i = 0; i < 4; i++)
#pragma unroll
      for (int j = 0; j < 4; j++) {
        acc[i][j] = __builtin_amdgcn_mfma_f32_16x16x32_bf16(aw[i][0], bw[j][0], acc[i][j], 0, 0, 0);
        acc[i][j] = __builtin_amdgcn_mfma_f32_16x16x32_bf16(aw[i][1], bw[j][1], acc[i][j], 0, 0, 0);
      }
    __syncthreads();                   // readers of p done; p^1 loads drained
    p ^= 1;
  }

  const float gamma = (float)gptr[0];
  float bv[4];
#pragma unroll
  for (int j = 0; j < 4; j++) bv[j] = bias[bx * 128 + wc + j * 16 + row16];

  if constexpr (EPI == 0) {
    // h = gelu(gamma*acc + bias) -> blocked+swizzled 128x64 tiles via LDS.
    // SEW=136: b128 readback stays 16B-aligned (272B row stride); scalar
    // write aliasing is 2-way (free).
    constexpr int SEW = 136;
    bf16_t* sE = sm;
#pragma unroll
    for (int i = 0; i < 4; i++) {
      const int rb = wr + i * 16 + quad * 4;
#pragma unroll
      for (int j = 0; j < 4; j++) {
        const int col = wc + j * 16 + row16;
#pragma unroll
        for (int r = 0; r < 4; r++)
          sE[(rb + r) * SEW + col] =
              (bf16_t)gelu_exact(__builtin_fmaf(gamma, acc[i][j][r], bv[j]));
      }
    }
    __syncthreads();
    bf16_t* hb = (bf16_t*)Cout;        // aux = k-tiles of h (H/64 = 48)
#pragma unroll
    for (int kh = 0; kh < 2; kh++) {
      bf16_t* ht = hb + ((size_t)by * aux + bx * 2 + kh) * 8192;
#pragma unroll
      for (int n = 0; n < 4; n++) {
        const int g = n * 256 + tid;   // chunk index r*8+slot within out tile
        const int r = g >> 3, slot = g & 7, c = slot ^ (r & 7);
        *(bf16x8*)(ht + g * 8) = *(const bf16x8*)(sE + r * SEW + kh * 64 + c * 8);
      }
    }
  } else {
    float* outp = (float*)Cout;        // aux = row stride (=768)
#pragma unroll
    for (int j = 0; j < 4; j++) {
      const int col = bx * 128 + wc + j * 16 + row16;
#pragma unroll
      for (int i = 0; i < 4; i++) {
        const int rb = by * 128 + wr + i * 16 + quad * 4;
#pragma unroll
        for (int r = 0; r < 4; r++)
          if (rb + r < Mvalid)
            outp[(size_t)(rb + r) * aux + col] = __builtin_fmaf(gamma, acc[i][j][r], bv[j]);
      }
    }
  }
}

extern "C" void kernel_launch(void* const* d_in, const int* in_sizes, int n_in,
                              void* d_out, int out_size, void* d_ws, size_t ws_size,
                              hipStream_t stream) {
  const float* x  = (const float*)d_in[0];
  const float* w1 = (const float*)d_in[1];
  const float* b1 = (const float*)d_in[2];
  const float* w2 = (const float*)d_in[3];
  const float* b2 = (const float*)d_in[4];
  float* out = (float*)d_out;

  const int M = 64 * 197;      // 12608
  const int Mpad = 12800;      // 50 * 256 (100 row-tiles of 128)
  const int D = 768, H = 3072;
  const int nW = H * D;        // 2359296

  char* ws = (char*)d_ws;
  double* part = (double*)ws;                      // [512] @ ws[0,4096)
  double* gammas = (double*)(ws + 4096);           // [2] own cacheline
  bf16_t* xb  = (bf16_t*)(ws + 4096 + 256);        // 100x12 tiles of 128x64
  bf16_t* w1q = xb + (size_t)Mpad * D;             // 24x12 tiles
  bf16_t* w2q = w1q + (size_t)H * D;               // 6x48 tiles
  bf16_t* hb  = w2q + (size_t)D * H;               // 100x48 tiles

  static bool attr_done = false;
  if (!attr_done) {
    (void)hipFuncSetAttribute(reinterpret_cast<const void*>(&gemm_db<0>),
                              hipFuncAttributeMaxDynamicSharedMemorySize, 65536);
    (void)hipFuncSetAttribute(reinterpret_cast<const void*>(&gemm_db<1>),
                              hipFuncAttributeMaxDynamicSharedMemorySize, 65536);
    attr_done = true;
  }

  reduce_part_kernel<<<512, 256, 0, stream>>>(w1, w2, nW, part);
  prep_kernel<<<2304 + 4800, 256, 0, stream>>>(w1, w2, x, part, gammas, w1q, w2q, xb);

  // GEMM1: 128x128 blocks, grid 100*24=2400 (2 blocks/CU); A=xb(nkt=12), B=w1q -> hb
  gemm_db<0><<<100 * 24, 256, 65536, stream>>>(xb, w1q, b1, gammas + 0, hb, 12, 24, M, H / 64);
  // GEMM2: 128x128 blocks, grid 100*6=600; A=hb(nkt=48), B=w2q -> fp32 out
  gemm_db<1><<<100 * 6, 256, 65536, stream>>>(hb, w2q, b2, gammas + 1, out, 48, 6, M, D);
}